// Round 5
// baseline (393.834 us; speedup 1.0000x reference)
//
#include <hip/hip_runtime.h>
#include <hip/hip_cooperative_groups.h>
#include <math.h>

namespace cg = cooperative_groups;

#define BATCH 4
#define SEQ   4096
#define DIM   1024
#define VEC   4

// Per-d parameters: a = phazor = p/|p| * exp(-|p|), b = phazor_init.
__device__ __forceinline__ void load_params4(
    const float* __restrict__ phr, const float* __restrict__ phi,
    const float* __restrict__ pir, const float* __restrict__ pii,
    int d0, float* ar, float* ai, float* br, float* bi)
{
    float4 p_r = *reinterpret_cast<const float4*>(phr + d0);
    float4 p_i = *reinterpret_cast<const float4*>(phi + d0);
    float4 q_r = *reinterpret_cast<const float4*>(pir + d0);
    float4 q_i = *reinterpret_cast<const float4*>(pii + d0);
    float prv[VEC] = {p_r.x, p_r.y, p_r.z, p_r.w};
    float piv[VEC] = {p_i.x, p_i.y, p_i.z, p_i.w};
    float qrv[VEC] = {q_r.x, q_r.y, q_r.z, q_r.w};
    float qiv[VEC] = {q_i.x, q_i.y, q_i.z, q_i.w};
#pragma unroll
    for (int j = 0; j < VEC; ++j) {
        float mag = sqrtf(prv[j] * prv[j] + piv[j] * piv[j]);
        float s = expf(-mag) / mag;
        ar[j] = prv[j] * s;
        ai[j] = piv[j] * s;
        br[j] = qrv[j];
        bi[j] = qiv[j];
    }
}

// ---------------- Cooperative single-kernel path ----------------
// NC=256 chunks of S=16. Grid = NC*BATCH = 1024 blocks = 4 blocks/CU x 256 CU
// (co-resident, validated by hipLaunchCooperativeKernel). Phase 1: x tile ->
// REGISTERS (S*VEC = 64 floats), zero-seeded local scan, publish carry.
// grid.sync. Phase 2: wave-parallel affine prefix per (b,d) (4096 waves =
// exactly this grid). grid.sync. Phase 3: replay from registers, write out.
// x is read from HBM exactly ONCE.
template <int NC, bool CPLX>
__global__ __launch_bounds__(256, 4) void k_coop(
    const float* __restrict__ x,
    const float* __restrict__ phr, const float* __restrict__ phi,
    const float* __restrict__ pir, const float* __restrict__ pii,
    const float* __restrict__ hr,  const float* __restrict__ hi_,
    float2* __restrict__ carry, float2* __restrict__ prefix,
    float* __restrict__ out)
{
    constexpr int S = SEQ / NC;   // 16
    constexpr int CPL = NC / 64;  // 4
    cg::grid_group gg = cg::this_grid();

    const int bid = blockIdx.x;
    const int c = bid / BATCH, b = bid % BATCH;
    const int d0 = threadIdx.x * VEC;

    // Phase 1: x tile into registers + zero-seeded local scan.
    float xr[S][VEC];
    {
        const float* xp = x + ((size_t)b * SEQ + (size_t)c * S) * DIM + d0;
#pragma unroll
        for (int t = 0; t < S; ++t)
            *reinterpret_cast<float4*>(xr[t]) =
                *reinterpret_cast<const float4*>(xp + (size_t)t * DIM);
    }
    {
        float ar[VEC], ai[VEC], br[VEC], bi[VEC];
        load_params4(phr, phi, pir, pii, d0, ar, ai, br, bi);
        float Cr[VEC] = {0.f,0.f,0.f,0.f}, Ci[VEC] = {0.f,0.f,0.f,0.f};
#pragma unroll
        for (int t = 0; t < S; ++t)
#pragma unroll
            for (int j = 0; j < VEC; ++j) {
                float nr = fmaf(ar[j], Cr[j], fmaf(-ai[j], Ci[j], br[j] * xr[t][j]));
                float ni = fmaf(ar[j], Ci[j], fmaf( ai[j], Cr[j], bi[j] * xr[t][j]));
                Cr[j] = nr; Ci[j] = ni;
            }
        float2* cp = carry + ((size_t)b * NC + c) * DIM + d0;
#pragma unroll
        for (int j = 0; j < VEC; ++j) cp[j] = make_float2(Cr[j], Ci[j]);
    }

    gg.sync();

    // Phase 2: wave-parallel prefix. wave = b2*DIM + d2.
    {
        const int wave = bid * 4 + (threadIdx.x >> 6);
        const int lane = threadIdx.x & 63;
        const int b2 = wave / DIM, d2 = wave % DIM;

        float pr = phr[d2], pi = phi[d2];
        float mag = sqrtf(pr * pr + pi * pi);
        float sc = expf(-mag) / mag;
        float a_r = pr * sc, a_i = pi * sc;
        // A = a^S by squaring.
        float Ar = 1.f, Ai = 0.f, sr = a_r, si = a_i;
        int e = S;
        while (e) {
            if (e & 1) { float nr = Ar * sr - Ai * si; Ai = Ar * si + Ai * sr; Ar = nr; }
            float nr = sr * sr - si * si; si = 2.f * sr * si; sr = nr;
            e >>= 1;
        }

        float2 cv[CPL];
#pragma unroll
        for (int j = 0; j < CPL; ++j)
            cv[j] = carry[((size_t)b2 * NC + lane * CPL + j) * DIM + d2];

        float mr = 1.f, mi = 0.f, rr = 0.f, ri = 0.f;
#pragma unroll
        for (int j = 0; j < CPL; ++j) {
            float nmr = Ar * mr - Ai * mi;
            float nmi = Ar * mi + Ai * mr;
            float nrr = fmaf(Ar, rr, fmaf(-Ai, ri, cv[j].x));
            float nri = fmaf(Ar, ri, fmaf( Ai, rr, cv[j].y));
            mr = nmr; mi = nmi; rr = nrr; ri = nri;
        }
#pragma unroll
        for (int off = 1; off < 64; off <<= 1) {
            float pmr = __shfl_up(mr, off);
            float pmi = __shfl_up(mi, off);
            float prr = __shfl_up(rr, off);
            float pri = __shfl_up(ri, off);
            if (lane >= off) {
                float nmr = mr * pmr - mi * pmi;
                float nmi = mr * pmi + mi * pmr;
                float nrr = fmaf(mr, prr, fmaf(-mi, pri, rr));
                float nri = fmaf(mr, pri, fmaf( mi, prr, ri));
                mr = nmr; mi = nmi; rr = nrr; ri = nri;
            }
        }
        float emr = __shfl_up(mr, 1);
        float emi = __shfl_up(mi, 1);
        float err_ = __shfl_up(rr, 1);
        float eri = __shfl_up(ri, 1);
        if (lane == 0) { emr = 1.f; emi = 0.f; err_ = 0.f; eri = 0.f; }

        float h_r = hr[wave], h_i = hi_[wave];
        float Pr = fmaf(emr, h_r, fmaf(-emi, h_i, err_));
        float Pi = fmaf(emr, h_i, fmaf( emi, h_r, eri));
#pragma unroll
        for (int j = 0; j < CPL; ++j) {
            prefix[((size_t)b2 * NC + lane * CPL + j) * DIM + d2] = make_float2(Pr, Pi);
            float nr = fmaf(Ar, Pr, fmaf(-Ai, Pi, cv[j].x));
            float ni = fmaf(Ar, Pi, fmaf( Ai, Pr, cv[j].y));
            Pr = nr; Pi = ni;
        }
    }

    gg.sync();

    // Phase 3: replay from registers seeded with prefix; write out.
    {
        float ar[VEC], ai[VEC], br[VEC], bi[VEC];
        load_params4(phr, phi, pir, pii, d0, ar, ai, br, bi);

        float Cr[VEC], Ci[VEC];
        const float2* pp = prefix + ((size_t)b * NC + c) * DIM + d0;
#pragma unroll
        for (int j = 0; j < VEC; ++j) {
            float2 v = pp[j];
            Cr[j] = v.x; Ci[j] = v.y;
        }

        const size_t obase = ((size_t)b * SEQ + (size_t)c * S) * DIM + d0;
#pragma unroll
        for (int t = 0; t < S; ++t) {
#pragma unroll
            for (int j = 0; j < VEC; ++j) {
                float nr = fmaf(ar[j], Cr[j], fmaf(-ai[j], Ci[j], br[j] * xr[t][j]));
                float ni = fmaf(ar[j], Ci[j], fmaf( ai[j], Cr[j], bi[j] * xr[t][j]));
                Cr[j] = nr; Ci[j] = ni;
            }
            if (CPLX) {
                float4* dst = reinterpret_cast<float4*>(out + 2 * (obase + (size_t)t * DIM));
                dst[0] = make_float4(Cr[0], Ci[0], Cr[1], Ci[1]);
                dst[1] = make_float4(Cr[2], Ci[2], Cr[3], Ci[3]);
            } else {
                *reinterpret_cast<float4*>(out + obase + (size_t)t * DIM) =
                    make_float4(Cr[0], Cr[1], Cr[2], Cr[3]);
            }
        }
    }
}

// ---------------- Fallback: known-good 3-dispatch path (R3) ----------------
template <int NC>
__global__ __launch_bounds__(256) void k_carry(
    const float* __restrict__ x,
    const float* __restrict__ phr, const float* __restrict__ phi,
    const float* __restrict__ pir, const float* __restrict__ pii,
    float2* __restrict__ carry)
{
    constexpr int S = SEQ / NC;
    const int d0 = (blockIdx.x * blockDim.x + threadIdx.x) * VEC;
    const int c = blockIdx.y, b = blockIdx.z;

    float ar[VEC], ai[VEC], br[VEC], bi[VEC];
    load_params4(phr, phi, pir, pii, d0, ar, ai, br, bi);

    const float* xp = x + ((size_t)b * SEQ + (size_t)c * S) * DIM + d0;
    float Cr[VEC] = {0.f,0.f,0.f,0.f}, Ci[VEC] = {0.f,0.f,0.f,0.f};
#pragma unroll 4
    for (int t = 0; t < S; ++t) {
        float4 xv = *reinterpret_cast<const float4*>(xp + (size_t)t * DIM);
        float xa[VEC] = {xv.x, xv.y, xv.z, xv.w};
#pragma unroll
        for (int j = 0; j < VEC; ++j) {
            float nr = fmaf(ar[j], Cr[j], fmaf(-ai[j], Ci[j], br[j] * xa[j]));
            float ni = fmaf(ar[j], Ci[j], fmaf( ai[j], Cr[j], bi[j] * xa[j]));
            Cr[j] = nr; Ci[j] = ni;
        }
    }
    float2* cp = carry + ((size_t)b * NC + c) * DIM + d0;
#pragma unroll
    for (int j = 0; j < VEC; ++j) cp[j] = make_float2(Cr[j], Ci[j]);
}

template <int NC>
__global__ __launch_bounds__(256) void k_prefix_wave(
    const float* __restrict__ phr, const float* __restrict__ phi,
    const float* __restrict__ hr,  const float* __restrict__ hi_,
    const float2* __restrict__ carry,
    float2* __restrict__ prefix)
{
    constexpr int S = SEQ / NC;
    constexpr int CPL = NC / 64;
    const int wave = (blockIdx.x * blockDim.x + threadIdx.x) >> 6;
    const int lane = threadIdx.x & 63;
    const int b = wave / DIM, d = wave % DIM;

    float pr = phr[d], pi = phi[d];
    float mag = sqrtf(pr * pr + pi * pi);
    float sc = expf(-mag) / mag;
    float a_r = pr * sc, a_i = pi * sc;
    float Ar = 1.f, Ai = 0.f, sr = a_r, si = a_i;
    int e = S;
    while (e) {
        if (e & 1) { float nr = Ar * sr - Ai * si; Ai = Ar * si + Ai * sr; Ar = nr; }
        float nr = sr * sr - si * si; si = 2.f * sr * si; sr = nr;
        e >>= 1;
    }

    float2 cv[CPL];
#pragma unroll
    for (int j = 0; j < CPL; ++j)
        cv[j] = carry[((size_t)b * NC + lane * CPL + j) * DIM + d];

    float mr = 1.f, mi = 0.f, rr = 0.f, ri = 0.f;
#pragma unroll
    for (int j = 0; j < CPL; ++j) {
        float nmr = Ar * mr - Ai * mi;
        float nmi = Ar * mi + Ai * mr;
        float nrr = fmaf(Ar, rr, fmaf(-Ai, ri, cv[j].x));
        float nri = fmaf(Ar, ri, fmaf( Ai, rr, cv[j].y));
        mr = nmr; mi = nmi; rr = nrr; ri = nri;
    }
#pragma unroll
    for (int off = 1; off < 64; off <<= 1) {
        float pmr = __shfl_up(mr, off);
        float pmi = __shfl_up(mi, off);
        float prr = __shfl_up(rr, off);
        float pri = __shfl_up(ri, off);
        if (lane >= off) {
            float nmr = mr * pmr - mi * pmi;
            float nmi = mr * pmi + mi * pmr;
            float nrr = fmaf(mr, prr, fmaf(-mi, pri, rr));
            float nri = fmaf(mr, pri, fmaf( mi, prr, ri));
            mr = nmr; mi = nmi; rr = nrr; ri = nri;
        }
    }
    float emr = __shfl_up(mr, 1);
    float emi = __shfl_up(mi, 1);
    float err_ = __shfl_up(rr, 1);
    float eri = __shfl_up(ri, 1);
    if (lane == 0) { emr = 1.f; emi = 0.f; err_ = 0.f; eri = 0.f; }

    float h_r = hr[wave], h_i = hi_[wave];
    float Pr = fmaf(emr, h_r, fmaf(-emi, h_i, err_));
    float Pi = fmaf(emr, h_i, fmaf( emi, h_r, eri));
#pragma unroll
    for (int j = 0; j < CPL; ++j) {
        prefix[((size_t)b * NC + lane * CPL + j) * DIM + d] = make_float2(Pr, Pi);
        float nr = fmaf(Ar, Pr, fmaf(-Ai, Pi, cv[j].x));
        float ni = fmaf(Ar, Pi, fmaf( Ai, Pr, cv[j].y));
        Pr = nr; Pi = ni;
    }
}

template <int NC, bool CPLX>
__global__ __launch_bounds__(256) void k_out(
    const float* __restrict__ x,
    const float* __restrict__ phr, const float* __restrict__ phi,
    const float* __restrict__ pir, const float* __restrict__ pii,
    const float2* __restrict__ prefix,
    float* __restrict__ out)
{
    constexpr int S = SEQ / NC;
    const int d0 = (blockIdx.x * blockDim.x + threadIdx.x) * VEC;
    const int c = blockIdx.y, b = blockIdx.z;

    float ar[VEC], ai[VEC], br[VEC], bi[VEC];
    load_params4(phr, phi, pir, pii, d0, ar, ai, br, bi);

    float Cr[VEC], Ci[VEC];
    const float2* pp = prefix + ((size_t)b * NC + c) * DIM + d0;
#pragma unroll
    for (int j = 0; j < VEC; ++j) {
        float2 v = pp[j];
        Cr[j] = v.x; Ci[j] = v.y;
    }

    const float* xp = x + ((size_t)b * SEQ + (size_t)c * S) * DIM + d0;
    const size_t obase = ((size_t)b * SEQ + (size_t)c * S) * DIM + d0;
#pragma unroll 2
    for (int t = 0; t < S; ++t) {
        float4 xv = *reinterpret_cast<const float4*>(xp + (size_t)t * DIM);
        float xa[VEC] = {xv.x, xv.y, xv.z, xv.w};
#pragma unroll
        for (int j = 0; j < VEC; ++j) {
            float nr = fmaf(ar[j], Cr[j], fmaf(-ai[j], Ci[j], br[j] * xa[j]));
            float ni = fmaf(ar[j], Ci[j], fmaf( ai[j], Cr[j], bi[j] * xa[j]));
            Cr[j] = nr; Ci[j] = ni;
        }
        if (CPLX) {
            float4* dst = reinterpret_cast<float4*>(out + 2 * (obase + (size_t)t * DIM));
            dst[0] = make_float4(Cr[0], Ci[0], Cr[1], Ci[1]);
            dst[1] = make_float4(Cr[2], Ci[2], Cr[3], Ci[3]);
        } else {
            *reinterpret_cast<float4*>(out + obase + (size_t)t * DIM) =
                make_float4(Cr[0], Cr[1], Cr[2], Cr[3]);
        }
    }
}

// Scratch-free last-resort fallback.
template <bool CPLX>
__global__ void k_serial(
    const float* __restrict__ x,
    const float* __restrict__ phr, const float* __restrict__ phi,
    const float* __restrict__ pir, const float* __restrict__ pii,
    const float* __restrict__ hr,  const float* __restrict__ hi_,
    float* __restrict__ out)
{
    const int idx = blockIdx.x * blockDim.x + threadIdx.x;
    if (idx >= BATCH * DIM) return;
    const int b = idx / DIM, d = idx % DIM;

    float pr = phr[d], pi = phi[d];
    float mag = sqrtf(pr * pr + pi * pi);
    float sc = expf(-mag) / mag;
    float ar = pr * sc, ai = pi * sc;
    float br = pir[d], bi = pii[d];

    float Cr = hr[idx], Ci = hi_[idx];
    const float* xp = x + (size_t)b * SEQ * DIM + d;
    for (int t = 0; t < SEQ; ++t) {
        float xv = xp[(size_t)t * DIM];
        float nr = fmaf(ar, Cr, fmaf(-ai, Ci, br * xv));
        float ni = fmaf(ar, Ci, fmaf( ai, Cr, bi * xv));
        Cr = nr; Ci = ni;
        size_t o = ((size_t)b * SEQ + t) * DIM + d;
        if (CPLX) reinterpret_cast<float2*>(out)[o] = make_float2(Cr, Ci);
        else      out[o] = Cr;
    }
}

template <int NC, bool CPLX>
static void run_fallback(const float* x, const float* hr, const float* hi_,
                         const float* phr, const float* phi,
                         const float* pir, const float* pii,
                         float* out, float2* carry, float2* prefix,
                         hipStream_t stream)
{
    dim3 blk(256);
    dim3 g1(DIM / (256 * VEC), NC, BATCH);
    k_carry<NC><<<g1, blk, 0, stream>>>(x, phr, phi, pir, pii, carry);
    k_prefix_wave<NC><<<dim3(BATCH * DIM * 64 / 256), blk, 0, stream>>>(
        phr, phi, hr, hi_, carry, prefix);
    k_out<NC, CPLX><<<g1, blk, 0, stream>>>(x, phr, phi, pir, pii, prefix, out);
}

template <bool CPLX>
static void dispatch(const float* x, const float* hr, const float* hi_,
                     const float* phr, const float* phi,
                     const float* pir, const float* pii,
                     float* out, void* d_ws, size_t ws_size, hipStream_t stream)
{
    constexpr int NC = 256;
    const size_t need = (size_t)2 * BATCH * NC * DIM * sizeof(float2);
    if (ws_size < need) {
        k_serial<CPLX><<<dim3((BATCH * DIM + 255) / 256), dim3(256), 0, stream>>>(
            x, phr, phi, pir, pii, hr, hi_, out);
        return;
    }
    float2* carry = (float2*)d_ws;
    float2* prefix = carry + (size_t)BATCH * NC * DIM;

    // Cooperative single-pass (x read once, grid-wide barriers, no spinning).
    const float* xa = x; const float* phra = phr; const float* phia = phi;
    const float* pira = pir; const float* piia = pii;
    const float* hra = hr; const float* hia = hi_;
    float2* ca = carry; float2* pa = prefix; float* oa = out;
    void* args[] = {(void*)&xa, (void*)&phra, (void*)&phia, (void*)&pira,
                    (void*)&piia, (void*)&hra, (void*)&hia,
                    (void*)&ca, (void*)&pa, (void*)&oa};
    hipError_t err = hipLaunchCooperativeKernel(
        (const void*)k_coop<NC, CPLX>, dim3(NC * BATCH), dim3(256),
        args, 0, stream);
    if (err != hipSuccess) {
        // Known-good 3-dispatch path.
        run_fallback<NC, CPLX>(x, hr, hi_, phr, phi, pir, pii,
                               out, carry, prefix, stream);
    }
}

extern "C" void kernel_launch(void* const* d_in, const int* in_sizes, int n_in,
                              void* d_out, int out_size, void* d_ws, size_t ws_size,
                              hipStream_t stream) {
    const float* x   = (const float*)d_in[0];
    const float* hr  = (const float*)d_in[1];
    const float* hi_ = (const float*)d_in[2];
    const float* phr = (const float*)d_in[3];
    const float* phi = (const float*)d_in[4];
    const float* pir = (const float*)d_in[5];
    const float* pii = (const float*)d_in[6];
    float* out = (float*)d_out;

    const size_t total = (size_t)BATCH * SEQ * DIM;
    if ((size_t)out_size >= 2 * total)
        dispatch<true >(x, hr, hi_, phr, phi, pir, pii, out, d_ws, ws_size, stream);
    else
        dispatch<false>(x, hr, hi_, phr, phi, pir, pii, out, d_ws, ws_size, stream);
}

// Round 7
// 174.836 us; speedup vs baseline: 2.2526x; 2.2526x over previous
//
#include <hip/hip_runtime.h>
#include <math.h>

#define BATCH 4
#define SEQ   4096
#define DIM   1024
#define VEC   4
#define NCC   128          // chunks; S = SEQ/NCC = 32

// Native clang vector type: required by __builtin_nontemporal_*.
typedef float vfloat4 __attribute__((ext_vector_type(4)));

__device__ __forceinline__ vfloat4 ntload4(const float* p) {
    return __builtin_nontemporal_load(reinterpret_cast<const vfloat4*>(p));
}
__device__ __forceinline__ void ntstore4(float* p, vfloat4 v) {
    __builtin_nontemporal_store(v, reinterpret_cast<vfloat4*>(p));
}

// Per-d parameters: a = phazor = p/|p| * exp(-|p|), b = phazor_init.
__device__ __forceinline__ void load_params4(
    const float* __restrict__ phr, const float* __restrict__ phi,
    const float* __restrict__ pir, const float* __restrict__ pii,
    int d0, float* ar, float* ai, float* br, float* bi)
{
    float4 p_r = *reinterpret_cast<const float4*>(phr + d0);
    float4 p_i = *reinterpret_cast<const float4*>(phi + d0);
    float4 q_r = *reinterpret_cast<const float4*>(pir + d0);
    float4 q_i = *reinterpret_cast<const float4*>(pii + d0);
    float prv[VEC] = {p_r.x, p_r.y, p_r.z, p_r.w};
    float piv[VEC] = {p_i.x, p_i.y, p_i.z, p_i.w};
    float qrv[VEC] = {q_r.x, q_r.y, q_r.z, q_r.w};
    float qiv[VEC] = {q_i.x, q_i.y, q_i.z, q_i.w};
#pragma unroll
    for (int j = 0; j < VEC; ++j) {
        float mag = sqrtf(prv[j] * prv[j] + piv[j] * piv[j]);
        float s = expf(-mag) / mag;
        ar[j] = prv[j] * s;
        ai[j] = piv[j] * s;
        br[j] = qrv[j];
        bi[j] = qiv[j];
    }
}

// A = a^S via exponentiation by squaring (complex).
__device__ __forceinline__ void pow_c(float a_r, float a_i, int e,
                                      float* outR, float* outI)
{
    float Ar = 1.f, Ai = 0.f, sr = a_r, si = a_i;
    while (e) {
        if (e & 1) { float nr = Ar * sr - Ai * si; Ai = Ar * si + Ai * sr; Ar = nr; }
        float nr = sr * sr - si * si; si = 2.f * sr * si; sr = nr;
        e >>= 1;
    }
    *outR = Ar; *outI = Ai;
}

// Pass 1: per-chunk local scan with zero initial state -> chunk carries.
// x loads are nontemporal (64 MB stream, no reuse until pass 2 anyway).
__global__ __launch_bounds__(256) void k_carry(
    const float* __restrict__ x,
    const float* __restrict__ phr, const float* __restrict__ phi,
    const float* __restrict__ pir, const float* __restrict__ pii,
    float2* __restrict__ carry)
{
    constexpr int S = SEQ / NCC;
    const int d0 = threadIdx.x * VEC;
    const int c = blockIdx.y, b = blockIdx.z;

    float ar[VEC], ai[VEC], br[VEC], bi[VEC];
    load_params4(phr, phi, pir, pii, d0, ar, ai, br, bi);

    const float* xp = x + ((size_t)b * SEQ + (size_t)c * S) * DIM + d0;
    float Cr[VEC] = {0.f,0.f,0.f,0.f}, Ci[VEC] = {0.f,0.f,0.f,0.f};
#pragma unroll 4
    for (int t = 0; t < S; ++t) {
        vfloat4 xv = ntload4(xp + (size_t)t * DIM);
        float xa[VEC] = {xv.x, xv.y, xv.z, xv.w};
#pragma unroll
        for (int j = 0; j < VEC; ++j) {
            float nr = fmaf(ar[j], Cr[j], fmaf(-ai[j], Ci[j], br[j] * xa[j]));
            float ni = fmaf(ar[j], Ci[j], fmaf( ai[j], Cr[j], bi[j] * xa[j]));
            Cr[j] = nr; Ci[j] = ni;
        }
    }
    // Regular (temporal) stores: carry array is re-read by k_out2.
    float4* cp4 = reinterpret_cast<float4*>(carry + ((size_t)b * NCC + c) * DIM + d0);
    cp4[0] = make_float4(Cr[0], Ci[0], Cr[1], Ci[1]);
    cp4[1] = make_float4(Cr[2], Ci[2], Cr[3], Ci[3]);
}

// Pass 2 (fused prefix + output): each block composes its own chunk seed from
// the carries (Horner: acc = sum_j W_j * agg[j], W *= A), then replays its
// chunk of x and writes complex64 out.  Compose math verified in R4's fused
// lookback (absmax 0.03125).  Carry loads batched 8-wide so they issue
// independently (no serial L2-latency chain).
template <bool CPLX>
__global__ __launch_bounds__(256) void k_out2(
    const float* __restrict__ x,
    const float* __restrict__ phr, const float* __restrict__ phi,
    const float* __restrict__ pir, const float* __restrict__ pii,
    const float* __restrict__ hr,  const float* __restrict__ hi_,
    const float2* __restrict__ carry,
    float* __restrict__ out)
{
    constexpr int S = SEQ / NCC;
    const int d0 = threadIdx.x * VEC;
    const int c = blockIdx.y, b = blockIdx.z;

    float ar[VEC], ai[VEC], br[VEC], bi[VEC];
    load_params4(phr, phi, pir, pii, d0, ar, ai, br, bi);

    float Ar[VEC], Ai[VEC];
#pragma unroll
    for (int j = 0; j < VEC; ++j) pow_c(ar[j], ai[j], S, &Ar[j], &Ai[j]);

    // Compose seed: P = sum_{j<c} A^{c-1-j} agg[j] + A^c h.
    float aR[VEC] = {0.f,0.f,0.f,0.f}, aI[VEC] = {0.f,0.f,0.f,0.f};
    float WR[VEC] = {1.f,1.f,1.f,1.f}, WI[VEC] = {0.f,0.f,0.f,0.f};
    int j = c - 1;
    while (j >= 0) {
        const int g = (j >= 7) ? 8 : (j + 1);
        float4 buf[8][2];
#pragma unroll
        for (int k = 0; k < 8; ++k) {
            if (k < g) {
                const float4* cp4 = reinterpret_cast<const float4*>(
                    carry + ((size_t)b * NCC + (j - k)) * DIM + d0);
                buf[k][0] = cp4[0];
                buf[k][1] = cp4[1];
            }
        }
#pragma unroll
        for (int k = 0; k < 8; ++k) {
            if (k < g) {
                float cr[VEC] = {buf[k][0].x, buf[k][0].z, buf[k][1].x, buf[k][1].z};
                float ci[VEC] = {buf[k][0].y, buf[k][0].w, buf[k][1].y, buf[k][1].w};
#pragma unroll
                for (int jj = 0; jj < VEC; ++jj) {
                    aR[jj] += WR[jj] * cr[jj] - WI[jj] * ci[jj];
                    aI[jj] += WR[jj] * ci[jj] + WI[jj] * cr[jj];
                    float nWR = WR[jj] * Ar[jj] - WI[jj] * Ai[jj];
                    WI[jj] = WR[jj] * Ai[jj] + WI[jj] * Ar[jj];
                    WR[jj] = nWR;
                }
            }
        }
        j -= g;
    }

    float Cr[VEC], Ci[VEC];
#pragma unroll
    for (int jj = 0; jj < VEC; ++jj) {
        float h_r = hr[b * DIM + d0 + jj];
        float h_i = hi_[b * DIM + d0 + jj];
        Cr[jj] = aR[jj] + WR[jj] * h_r - WI[jj] * h_i;
        Ci[jj] = aI[jj] + WR[jj] * h_i + WI[jj] * h_r;
    }

    // Replay chunk; x and out are pure streams -> nontemporal.
    const float* xp = x + ((size_t)b * SEQ + (size_t)c * S) * DIM + d0;
    const size_t obase = ((size_t)b * SEQ + (size_t)c * S) * DIM + d0;
#pragma unroll 2
    for (int t = 0; t < S; ++t) {
        vfloat4 xv = ntload4(xp + (size_t)t * DIM);
        float xa[VEC] = {xv.x, xv.y, xv.z, xv.w};
#pragma unroll
        for (int jj = 0; jj < VEC; ++jj) {
            float nr = fmaf(ar[jj], Cr[jj], fmaf(-ai[jj], Ci[jj], br[jj] * xa[jj]));
            float ni = fmaf(ar[jj], Ci[jj], fmaf( ai[jj], Cr[jj], bi[jj] * xa[jj]));
            Cr[jj] = nr; Ci[jj] = ni;
        }
        if (CPLX) {
            float* dst = out + 2 * (obase + (size_t)t * DIM);
            vfloat4 o0 = {Cr[0], Ci[0], Cr[1], Ci[1]};
            vfloat4 o1 = {Cr[2], Ci[2], Cr[3], Ci[3]};
            ntstore4(dst,     o0);
            ntstore4(dst + 4, o1);
        } else {
            vfloat4 o0 = {Cr[0], Cr[1], Cr[2], Cr[3]};
            ntstore4(out + obase + (size_t)t * DIM, o0);
        }
    }
}

// Scratch-free last-resort fallback (ws too small; should never trigger).
template <bool CPLX>
__global__ void k_serial(
    const float* __restrict__ x,
    const float* __restrict__ phr, const float* __restrict__ phi,
    const float* __restrict__ pir, const float* __restrict__ pii,
    const float* __restrict__ hr,  const float* __restrict__ hi_,
    float* __restrict__ out)
{
    const int idx = blockIdx.x * blockDim.x + threadIdx.x;
    if (idx >= BATCH * DIM) return;
    const int b = idx / DIM, d = idx % DIM;

    float pr = phr[d], pi = phi[d];
    float mag = sqrtf(pr * pr + pi * pi);
    float sc = expf(-mag) / mag;
    float ar = pr * sc, ai = pi * sc;
    float br = pir[d], bi = pii[d];

    float Cr = hr[idx], Ci = hi_[idx];
    const float* xp = x + (size_t)b * SEQ * DIM + d;
    for (int t = 0; t < SEQ; ++t) {
        float xv = xp[(size_t)t * DIM];
        float nr = fmaf(ar, Cr, fmaf(-ai, Ci, br * xv));
        float ni = fmaf(ar, Ci, fmaf( ai, Cr, bi * xv));
        Cr = nr; Ci = ni;
        size_t o = ((size_t)b * SEQ + t) * DIM + d;
        if (CPLX) reinterpret_cast<float2*>(out)[o] = make_float2(Cr, Ci);
        else      out[o] = Cr;
    }
}

template <bool CPLX>
static void dispatch(const float* x, const float* hr, const float* hi_,
                     const float* phr, const float* phi,
                     const float* pir, const float* pii,
                     float* out, void* d_ws, size_t ws_size, hipStream_t stream)
{
    const size_t need = (size_t)BATCH * NCC * DIM * sizeof(float2);  // 4 MB
    if (ws_size < need) {
        k_serial<CPLX><<<dim3((BATCH * DIM + 255) / 256), dim3(256), 0, stream>>>(
            x, phr, phi, pir, pii, hr, hi_, out);
        return;
    }
    float2* carry = (float2*)d_ws;

    dim3 blk(256);
    dim3 g1(1, NCC, BATCH);   // 512 blocks, 2/CU
    k_carry<<<g1, blk, 0, stream>>>(x, phr, phi, pir, pii, carry);
    k_out2<CPLX><<<g1, blk, 0, stream>>>(x, phr, phi, pir, pii, hr, hi_,
                                         carry, out);
}

extern "C" void kernel_launch(void* const* d_in, const int* in_sizes, int n_in,
                              void* d_out, int out_size, void* d_ws, size_t ws_size,
                              hipStream_t stream) {
    const float* x   = (const float*)d_in[0];
    const float* hr  = (const float*)d_in[1];
    const float* hi_ = (const float*)d_in[2];
    const float* phr = (const float*)d_in[3];
    const float* phi = (const float*)d_in[4];
    const float* pir = (const float*)d_in[5];
    const float* pii = (const float*)d_in[6];
    float* out = (float*)d_out;

    const size_t total = (size_t)BATCH * SEQ * DIM;
    if ((size_t)out_size >= 2 * total)
        dispatch<true >(x, hr, hi_, phr, phi, pir, pii, out, d_ws, ws_size, stream);
    else
        dispatch<false>(x, hr, hi_, phr, phi, pir, pii, out, d_ws, ws_size, stream);
}